// Round 4
// baseline (217.659 us; speedup 1.0000x reference)
//
#include <hip/hip_runtime.h>
#include <hip/hip_bf16.h>
#include <stdint.h>

#define B_DIM 8
#define T_DIM 2048
#define H_DIM 512
#define NC 32       // chunks per batch
#define LCH 64      // chunk length
#define NSUB 4      // sub-chunks per chunk
#define LSUB 16     // steps per sub-chunk
#define NSEG (NC * NSUB)   // 128 segments per batch
#define NOCT 8             // octets per batch (16 segments each)
#define BM 256
#define BN 256
#define BK 64

typedef float floatx4 __attribute__((ext_vector_type(4)));
typedef __bf16 bf16x4 __attribute__((ext_vector_type(4)));
typedef __bf16 bf16x8 __attribute__((ext_vector_type(8)));

// ---------------- K1: global min/max of e -> stats[0]=mn, stats[1]=1/(mx-mn)
__global__ __launch_bounds__(1024) void minmax_kernel(const float* __restrict__ e,
                                                      float* __restrict__ stats) {
    const float4* e4 = (const float4*)e;
    int tid = threadIdx.x;
    float mn = 1e30f, mx = -1e30f;
    #pragma unroll
    for (int i = 0; i < 4; ++i) {
        float4 v = e4[tid + i * 1024];
        mn = fminf(mn, fminf(fminf(v.x, v.y), fminf(v.z, v.w)));
        mx = fmaxf(mx, fmaxf(fmaxf(v.x, v.y), fmaxf(v.z, v.w)));
    }
    for (int off = 32; off > 0; off >>= 1) {
        mn = fminf(mn, __shfl_down(mn, off, 64));
        mx = fmaxf(mx, __shfl_down(mx, off, 64));
    }
    __shared__ float smn[16], smx[16];
    int wid = tid >> 6;
    if ((tid & 63) == 0) { smn[wid] = mn; smx[wid] = mx; }
    __syncthreads();
    if (tid == 0) {
        mn = smn[0]; mx = smx[0];
        #pragma unroll
        for (int w = 1; w < 16; ++w) { mn = fminf(mn, smn[w]); mx = fmaxf(mx, smx[w]); }
        stats[0] = mn;
        stats[1] = 1.0f / (mx - mn);
    }
}

// ---------------- K2: per-sub-chunk local scan (zero-init), emit h_bf + per-sub summaries.
__global__ __launch_bounds__(512) void chunk_sum_kernel(
        const float* __restrict__ e, const float* __restrict__ h,
        const float* __restrict__ stats,
        __hip_bfloat16* __restrict__ h_bf,
        float* __restrict__ Lsub, float* __restrict__ PPsub, float* __restrict__ LDsub) {
    const int b = blockIdx.x, c = blockIdx.y;
    const int tid = threadIdx.x;
    const int hdq = tid & 127, sub = tid >> 7;
    const int hd = hdq * 4;
    const int t0 = c * LCH + sub * LSUB;

    __shared__ float se[LCH];   // multiplier a for step j of this chunk
    if (tid < LCH) {
        int t = c * LCH + tid;
        se[tid] = (t == 0) ? 0.0f : (e[b * T_DIM + t - 1] - stats[0]) * stats[1];
    }
    __syncthreads();

    const float* hp = h + ((size_t)b * T_DIM + t0) * H_DIM + hd;
    __hip_bfloat16* hbp = h_bf + ((size_t)b * T_DIM + t0) * H_DIM + hd;

    floatx4 lv = {0.0f, 0.0f, 0.0f, 0.0f};
    float ldv = 0.0f, pp = 1.0f;
    #pragma unroll 8
    for (int i = 0; i < LSUB; ++i) {
        float a = se[sub * LSUB + i];
        floatx4 hv = *(const floatx4*)(hp + (size_t)i * H_DIM);
        lv = a * lv + hv;
        ldv = fmaf(a, ldv, 1.0f);
        pp *= a;
        bf16x4 o;
        #pragma unroll
        for (int k = 0; k < 4; ++k) o[k] = (__bf16)hv[k];
        *(bf16x4*)(hbp + (size_t)i * H_DIM) = o;
    }
    int seg = (b * NC + c) * NSUB + sub;
    *(floatx4*)(Lsub + (size_t)seg * H_DIM + hd) = lv;
    if (hdq == 0) { PPsub[seg] = pp; LDsub[seg] = ldv; }
}

// ---------------- K3a: per-octet affine composition over its 16 segments.
__global__ __launch_bounds__(512) void octet_kernel(
        const float* __restrict__ Lsub, const float* __restrict__ PPsub,
        const float* __restrict__ LDsub,
        float* __restrict__ Loct, float* __restrict__ Poct, float* __restrict__ LDoct) {
    const int b = blockIdx.x, o = blockIdx.y, hd = threadIdx.x;
    float lc = 0.0f, ldc = 0.0f, P = 1.0f;
    #pragma unroll 4
    for (int i = 0; i < 16; ++i) {
        int seg = b * NSEG + o * 16 + i;
        float pe = PPsub[seg];
        lc  = fmaf(pe, lc,  Lsub[(size_t)seg * H_DIM + hd]);
        ldc = fmaf(pe, ldc, LDsub[seg]);
        P *= pe;
    }
    int oc = b * NOCT + o;
    Loct[(size_t)oc * H_DIM + hd] = lc;
    if (hd == 0) { Poct[oc] = P; LDoct[oc] = ldc; }
}

// ---------------- K3b: serial fold over 8 octets -> octet entering states.
__global__ __launch_bounds__(512) void octfold_kernel(
        const float* __restrict__ Loct, const float* __restrict__ Poct,
        const float* __restrict__ LDoct,
        float* __restrict__ Soct, float* __restrict__ SDoct) {
    const int b = blockIdx.x, hd = threadIdx.x;
    float s = 0.0f, sd = 0.0f;
    #pragma unroll
    for (int o = 0; o < NOCT; ++o) {
        int oc = b * NOCT + o;
        Soct[(size_t)oc * H_DIM + hd] = s;
        if (hd == 0) SDoct[oc] = sd;
        float P = Poct[oc];
        s  = fmaf(P, s,  Loct[(size_t)oc * H_DIM + hd]);
        sd = fmaf(P, sd, LDoct[oc]);
    }
}

// ---------------- K3c: re-fold within each octet -> per-segment entering states.
__global__ __launch_bounds__(512) void segfold_kernel(
        const float* __restrict__ Lsub, const float* __restrict__ PPsub,
        const float* __restrict__ LDsub,
        const float* __restrict__ Soct, const float* __restrict__ SDoct,
        float* __restrict__ Ssub, float* __restrict__ SDsub) {
    const int b = blockIdx.x, o = blockIdx.y, hd = threadIdx.x;
    int oc = b * NOCT + o;
    float s = Soct[(size_t)oc * H_DIM + hd];
    float sd = SDoct[oc];
    #pragma unroll 4
    for (int i = 0; i < 16; ++i) {
        int seg = b * NSEG + o * 16 + i;
        Ssub[(size_t)seg * H_DIM + hd] = s;
        if (hd == 0) SDsub[seg] = sd;
        float pe = PPsub[seg];
        s  = fmaf(pe, s,  Lsub[(size_t)seg * H_DIM + hd]);
        sd = fmaf(pe, sd, LDsub[seg]);
    }
}

// ---------------- K4: rescan sub-chunk from h_bf with carried-in state -> h_agg (bf16).
__global__ __launch_bounds__(512) void rescan_kernel(
        const float* __restrict__ e, const __hip_bfloat16* __restrict__ h_bf,
        const float* __restrict__ stats,
        const float* __restrict__ Ssub, const float* __restrict__ SDsub,
        __hip_bfloat16* __restrict__ hagg_bf) {
    const int b = blockIdx.x, c = blockIdx.y;
    const int tid = threadIdx.x;
    const int hdq = tid & 127, sub = tid >> 7;
    const int hd = hdq * 4;
    const int t0 = c * LCH + sub * LSUB;

    __shared__ float se[LCH];
    if (tid < LCH) {
        int t = c * LCH + tid;
        se[tid] = (t == 0) ? 0.0f : (e[b * T_DIM + t - 1] - stats[0]) * stats[1];
    }
    __syncthreads();

    const int seg = (b * NC + c) * NSUB + sub;
    const __hip_bfloat16* hbp = h_bf + ((size_t)b * T_DIM + t0) * H_DIM + hd;
    __hip_bfloat16* hop = hagg_bf + ((size_t)b * T_DIM + t0) * H_DIM + hd;

    floatx4 s = *(const floatx4*)(Ssub + (size_t)seg * H_DIM + hd);
    float sd = SDsub[seg];
    #pragma unroll 8
    for (int i = 0; i < LSUB; ++i) {
        float a = se[sub * LSUB + i];
        bf16x4 hb = *(const bf16x4*)(hbp + (size_t)i * H_DIM);
        floatx4 hv;
        #pragma unroll
        for (int k = 0; k < 4; ++k) hv[k] = (float)hb[k];
        s = a * s + hv;
        sd = fmaf(a, sd, 1.0f);
        float inv = 1.0f / sd;
        bf16x4 o;
        #pragma unroll
        for (int k = 0; k < 4; ++k) o[k] = (__bf16)(s[k] * inv);
        *(bf16x4*)(hop + (size_t)i * H_DIM) = o;
    }
}

// ---------------- K5: batched NT-GEMM, C[b,t,s] = (1/sqrt(H)) * A[b,t,:] . B[b,s,:]
// 256x256 tile, 512 threads (8 waves 2Mx4N), BK=64, double-buffered 128 KiB LDS.
// FINE-PHASE schedule (T3+T4+T5): per K-tile, 4 phases of
//   { ds_read frags || issue 2 global_load_lds for tile t+1 -> barrier ->
//     setprio(1) -> 16 MFMA -> setprio(0) -> barrier }.
// Correctness-critical sync = ONE vmcnt(0)+barrier per K-tile boundary (same
// invariant as the verified r2 kernel); intra-tile barriers are scheduling-only
// (reads hit buf[cur], stage-writes hit buf[cur^1] — disjoint).
__device__ __forceinline__ void async16(const void* g, void* l) {
    __builtin_amdgcn_global_load_lds(
        (__attribute__((address_space(1))) void*)g,
        (__attribute__((address_space(3))) void*)l,
        16, 0, 0);
}

__global__ __launch_bounds__(512, 2) void gemm_kernel(
        const __hip_bfloat16* __restrict__ Abf,   // h_bf   [B][T][H]
        const __hip_bfloat16* __restrict__ Bbf,   // hagg_bf[B][T][H]
        float* __restrict__ C) {                  // [B][T][T]
    __shared__ __align__(16) char lds[131072];
    char* AsB = lds;
    char* BsB = lds + 65536;

    // Batch-per-XCD pin (id%8 == batch): 4 MB A+B per batch stays L2-resident.
    const int id = blockIdx.x + (blockIdx.y << 3) + (blockIdx.z << 6);
    const int b  = id & 7;
    const int tt = id >> 3;
    const int tm = (tt & 7) * BM;
    const int sn = (tt >> 3) * BN;

    const int tid = threadIdx.x;
    const int lane = tid & 63;
    const int wave = tid >> 6;
    const int wm = (wave >> 2) * 128;   // 2 wave-rows of 128
    const int wn = (wave & 3) * 64;     // 4 wave-cols of 64
    const int l16 = lane & 15;
    const int quad = lane >> 4;

    // Staging: thread covers rows (tid>>3)+q*64, granule slot tid&7; slot g of
    // row r holds global k-granule g ^ (r&7) (XOR swizzle on the GLOBAL source;
    // LDS dest stays linear as global_load_lds requires).
    const int srow = tid >> 3;
    const int sgran = (tid & 7) ^ (srow & 7);
    const __hip_bfloat16* Ag = Abf + ((size_t)b * T_DIM + tm + srow) * H_DIM + sgran * 8;
    const __hip_bfloat16* Bg = Bbf + ((size_t)b * T_DIM + sn + srow) * H_DIM + sgran * 8;

    floatx4 zero = {0.0f, 0.0f, 0.0f, 0.0f};
    floatx4 acc[8][4];
    #pragma unroll
    for (int i = 0; i < 8; ++i)
        #pragma unroll
        for (int j = 0; j < 4; ++j) acc[i][j] = zero;

    // Prologue: stage tile 0 into buffer 0 (8 loads/thread).
    #pragma unroll
    for (int q = 0; q < 4; ++q) {
        async16(Ag + (size_t)(q * 64) * H_DIM, AsB + q * 8192 + tid * 16);
        async16(Bg + (size_t)(q * 64) * H_DIM, BsB + q * 8192 + tid * 16);
    }

    const int NT = H_DIM / BK;   // 8 K-tiles
    for (int t = 0; t < NT; ++t) {
        const int cur = t & 1;
        // Boundary: tile t's loads (issued last iteration, >=1 phase old,
        // L2-resident) must have landed for every wave before reading buf[cur].
        asm volatile("s_waitcnt vmcnt(0)" ::: "memory");
        __builtin_amdgcn_s_barrier();

        const char* Ab = AsB + cur * 32768;
        const char* Bb = BsB + cur * 32768;
        bf16x8 bv[4];
        #pragma unroll
        for (int p = 0; p < 4; ++p) {
            const int ku = p >> 1, ih = p & 1;
            if (ih == 0) {
                #pragma unroll
                for (int j = 0; j < 4; ++j) {
                    int rb = wn + j * 16 + l16;
                    int gb = (ku * 4 + quad) ^ (l16 & 7);
                    bv[j] = *reinterpret_cast<const bf16x8*>(Bb + rb * 128 + gb * 16);
                }
            }
            bf16x8 av[4];
            #pragma unroll
            for (int i2 = 0; i2 < 4; ++i2) {
                int ra = wm + (ih * 4 + i2) * 16 + l16;
                int ga = (ku * 4 + quad) ^ (l16 & 7);
                av[i2] = *reinterpret_cast<const bf16x8*>(Ab + ra * 128 + ga * 16);
            }
            if (t < NT - 1) {   // spread tile t+1 staging: one row-quarter per phase
                const int kk_ = (t + 1) * BK;
                const int nb = cur ^ 1;
                async16(Ag + (size_t)(p * 64) * H_DIM + kk_, AsB + nb * 32768 + p * 8192 + tid * 16);
                async16(Bg + (size_t)(p * 64) * H_DIM + kk_, BsB + nb * 32768 + p * 8192 + tid * 16);
            }
            __builtin_amdgcn_s_barrier();   // phase entry (scheduling only)
            __builtin_amdgcn_s_setprio(1);
            #pragma unroll
            for (int i2 = 0; i2 < 4; ++i2)
                #pragma unroll
                for (int j = 0; j < 4; ++j)
                    acc[ih * 4 + i2][j] = __builtin_amdgcn_mfma_f32_16x16x32_bf16(
                        bv[j], av[i2], acc[ih * 4 + i2][j], 0, 0, 0);
            __builtin_amdgcn_s_setprio(0);
            __builtin_amdgcn_s_barrier();   // phase exit (scheduling only)
        }
    }

    const float scale = 0.04419417382415922f;  // 1/sqrt(512)
    float* Cp = C + (size_t)b * T_DIM * T_DIM;
    // Swapped-operand D mapping: col(lane&15) -> t (A-row), row(quad*4+r) -> s (B-row).
    #pragma unroll
    for (int i = 0; i < 8; ++i) {
        int row = tm + wm + i * 16 + l16;              // t
        float* crow = Cp + (size_t)row * T_DIM;
        #pragma unroll
        for (int j = 0; j < 4; ++j) {
            int col = sn + wn + j * 16 + quad * 4;     // s base (16B aligned)
            floatx4 v;
            #pragma unroll
            for (int r = 0; r < 4; ++r) v[r] = acc[i][j][r] * scale;
            *(floatx4*)(crow + col) = v;
        }
    }
}

extern "C" void kernel_launch(void* const* d_in, const int* in_sizes, int n_in,
                              void* d_out, int out_size, void* d_ws, size_t ws_size,
                              hipStream_t stream) {
    const float* e = (const float*)d_in[0];
    const float* h = (const float*)d_in[1];
    // d_in[2] (ilens) is unused by the reference output.
    float* out = (float*)d_out;

    char* ws = (char*)d_ws;
    float* stats            = (float*)ws;                                    // 256 B
    __hip_bfloat16* h_bf    = (__hip_bfloat16*)(ws + 4096);                  // 16 MB
    __hip_bfloat16* hagg_bf = (__hip_bfloat16*)(ws + 4096 + (16u << 20));    // 16 MB
    char* p = ws + 4096 + (32u << 20);
    float* Lsub  = (float*)p;   p += (size_t)B_DIM * NSEG * H_DIM * 4;       // 2 MB
    float* Ssub  = (float*)p;   p += (size_t)B_DIM * NSEG * H_DIM * 4;       // 2 MB
    float* PPsub = (float*)p;   p += B_DIM * NSEG * 4;                       // 4 KB
    float* LDsub = (float*)p;   p += B_DIM * NSEG * 4;                       // 4 KB
    float* SDsub = (float*)p;   p += B_DIM * NSEG * 4;                       // 4 KB
    float* Loct  = (float*)p;   p += (size_t)B_DIM * NOCT * H_DIM * 4;       // 128 KB
    float* Soct  = (float*)p;   p += (size_t)B_DIM * NOCT * H_DIM * 4;       // 128 KB
    float* Poct  = (float*)p;   p += B_DIM * NOCT * 4;                       // 256 B
    float* LDoct = (float*)p;   p += B_DIM * NOCT * 4;                       // 256 B
    float* SDoct = (float*)p;

    minmax_kernel<<<1, 1024, 0, stream>>>(e, stats);
    chunk_sum_kernel<<<dim3(B_DIM, NC), 512, 0, stream>>>(e, h, stats, h_bf, Lsub, PPsub, LDsub);
    octet_kernel<<<dim3(B_DIM, NOCT), 512, 0, stream>>>(Lsub, PPsub, LDsub, Loct, Poct, LDoct);
    octfold_kernel<<<B_DIM, 512, 0, stream>>>(Loct, Poct, LDoct, Soct, SDoct);
    segfold_kernel<<<dim3(B_DIM, NOCT), 512, 0, stream>>>(Lsub, PPsub, LDsub, Soct, SDoct, Ssub, SDsub);
    rescan_kernel<<<dim3(B_DIM, NC), 512, 0, stream>>>(e, h_bf, stats, Ssub, SDsub, hagg_bf);
    gemm_kernel<<<dim3(8, 8, B_DIM), 512, 0, stream>>>(h_bf, hagg_bf, out);
}

// Round 5
// 208.146 us; speedup vs baseline: 1.0457x; 1.0457x over previous
//
#include <hip/hip_runtime.h>
#include <hip/hip_bf16.h>
#include <stdint.h>

#define B_DIM 8
#define T_DIM 2048
#define H_DIM 512
#define NC 32       // chunks per batch
#define LCH 64      // chunk length
#define NSUB 4      // sub-chunks per chunk
#define LSUB 16     // steps per sub-chunk
#define NSEG (NC * NSUB)   // 128 segments per batch
#define NOCT 8             // octets per batch (16 segments each)
#define BM 128
#define BN 128
#define BK 64

typedef float floatx4 __attribute__((ext_vector_type(4)));
typedef __bf16 bf16x4 __attribute__((ext_vector_type(4)));
typedef __bf16 bf16x8 __attribute__((ext_vector_type(8)));

// Block-local recompute of global min/max of e (64 KB, L2-broadcast; fmin/fmax
// are order-independent so this is bit-identical to a dedicated pass).
// Returns via sst[0]=mn, sst[1]=1/(mx-mn). Requires 512 threads.
__device__ __forceinline__ void block_minmax(const float* __restrict__ e,
                                             float* __restrict__ sst /*LDS[2]*/,
                                             float* __restrict__ smn /*LDS[8]*/,
                                             float* __restrict__ smx /*LDS[8]*/) {
    const int tid = threadIdx.x;
    const float4* e4 = (const float4*)e;
    float mn = 1e30f, mx = -1e30f;
    #pragma unroll
    for (int i = 0; i < 8; ++i) {
        float4 v = e4[tid + i * 512];
        mn = fminf(mn, fminf(fminf(v.x, v.y), fminf(v.z, v.w)));
        mx = fmaxf(mx, fmaxf(fmaxf(v.x, v.y), fmaxf(v.z, v.w)));
    }
    #pragma unroll
    for (int off = 32; off > 0; off >>= 1) {
        mn = fminf(mn, __shfl_down(mn, off, 64));
        mx = fmaxf(mx, __shfl_down(mx, off, 64));
    }
    const int wid = tid >> 6;
    if ((tid & 63) == 0) { smn[wid] = mn; smx[wid] = mx; }
    __syncthreads();
    if (tid == 0) {
        mn = smn[0]; mx = smx[0];
        #pragma unroll
        for (int w = 1; w < 8; ++w) { mn = fminf(mn, smn[w]); mx = fmaxf(mx, smx[w]); }
        sst[0] = mn;
        sst[1] = 1.0f / (mx - mn);
    }
    __syncthreads();
}

// ---------------- K1: per-sub-chunk local scan (zero-init), emit h_bf + per-sub summaries.
__global__ __launch_bounds__(512) void chunk_sum_kernel(
        const float* __restrict__ e, const float* __restrict__ h,
        __hip_bfloat16* __restrict__ h_bf,
        float* __restrict__ Lsub, float* __restrict__ PPsub, float* __restrict__ LDsub) {
    const int b = blockIdx.x, c = blockIdx.y;
    const int tid = threadIdx.x;
    const int hdq = tid & 127, sub = tid >> 7;
    const int hd = hdq * 4;
    const int t0 = c * LCH + sub * LSUB;

    __shared__ float sst[2], smn[8], smx[8];
    __shared__ float se[LCH];   // multiplier a for step j of this chunk
    block_minmax(e, sst, smn, smx);

    if (tid < LCH) {
        int t = c * LCH + tid;
        se[tid] = (t == 0) ? 0.0f : (e[b * T_DIM + t - 1] - sst[0]) * sst[1];
    }
    __syncthreads();

    const float* hp = h + ((size_t)b * T_DIM + t0) * H_DIM + hd;
    __hip_bfloat16* hbp = h_bf + ((size_t)b * T_DIM + t0) * H_DIM + hd;

    floatx4 lv = {0.0f, 0.0f, 0.0f, 0.0f};
    float ldv = 0.0f, pp = 1.0f;
    #pragma unroll 8
    for (int i = 0; i < LSUB; ++i) {
        float a = se[sub * LSUB + i];
        floatx4 hv = *(const floatx4*)(hp + (size_t)i * H_DIM);
        lv = a * lv + hv;
        ldv = fmaf(a, ldv, 1.0f);
        pp *= a;
        bf16x4 o;
        #pragma unroll
        for (int k = 0; k < 4; ++k) o[k] = (__bf16)hv[k];
        *(bf16x4*)(hbp + (size_t)i * H_DIM) = o;
    }
    int seg = (b * NC + c) * NSUB + sub;
    *(floatx4*)(Lsub + (size_t)seg * H_DIM + hd) = lv;
    if (hdq == 0) { PPsub[seg] = pp; LDsub[seg] = ldv; }
}

// ---------------- K2: per-octet ZERO-SEEDED prefixes + octet aggregate, one pass.
// For octet segments i=0..15: Spart_i = prefix of affine maps 0..i-1 applied to 0,
// Ppre_i = product of pp over 0..i-1 (the seed multiplier). Aggregate = i=16 values.
// True entering state later: S_i = Ppre_i * Soct + Spart_i (exact affine identity;
// sd uses the SAME Ppre since its recurrence shares pe).
__global__ __launch_bounds__(512) void octprefix_kernel(
        const float* __restrict__ Lsub, const float* __restrict__ PPsub,
        const float* __restrict__ LDsub,
        float* __restrict__ Spart, float* __restrict__ Ppre, float* __restrict__ SDpart,
        float* __restrict__ Loct, float* __restrict__ Poct, float* __restrict__ LDoct) {
    const int b = blockIdx.x, o = blockIdx.y, hd = threadIdx.x;
    float sp = 0.0f, sdp = 0.0f, pp = 1.0f;
    #pragma unroll 4
    for (int i = 0; i < 16; ++i) {
        int seg = b * NSEG + o * 16 + i;
        Spart[(size_t)seg * H_DIM + hd] = sp;
        if (hd == 0) { Ppre[seg] = pp; SDpart[seg] = sdp; }
        float pe = PPsub[seg];
        sp  = fmaf(pe, sp,  Lsub[(size_t)seg * H_DIM + hd]);
        sdp = fmaf(pe, sdp, LDsub[seg]);
        pp *= pe;
    }
    int oc = b * NOCT + o;
    Loct[(size_t)oc * H_DIM + hd] = sp;
    if (hd == 0) { Poct[oc] = pp; LDoct[oc] = sdp; }
}

// ---------------- K3: serial fold over 8 octets -> octet entering states.
__global__ __launch_bounds__(512) void octfold_kernel(
        const float* __restrict__ Loct, const float* __restrict__ Poct,
        const float* __restrict__ LDoct,
        float* __restrict__ Soct, float* __restrict__ SDoct) {
    const int b = blockIdx.x, hd = threadIdx.x;
    float s = 0.0f, sd = 0.0f;
    #pragma unroll
    for (int o = 0; o < NOCT; ++o) {
        int oc = b * NOCT + o;
        Soct[(size_t)oc * H_DIM + hd] = s;
        if (hd == 0) SDoct[oc] = sd;
        float P = Poct[oc];
        s  = fmaf(P, s,  Loct[(size_t)oc * H_DIM + hd]);
        sd = fmaf(P, sd, LDoct[oc]);
    }
}

// ---------------- K4: rescan sub-chunk from h_bf; seed = Ppre*Soct + Spart.
__global__ __launch_bounds__(512) void rescan_kernel(
        const float* __restrict__ e, const __hip_bfloat16* __restrict__ h_bf,
        const float* __restrict__ Spart, const float* __restrict__ Ppre,
        const float* __restrict__ SDpart,
        const float* __restrict__ Soct, const float* __restrict__ SDoct,
        __hip_bfloat16* __restrict__ hagg_bf) {
    const int b = blockIdx.x, c = blockIdx.y;
    const int tid = threadIdx.x;
    const int hdq = tid & 127, sub = tid >> 7;
    const int hd = hdq * 4;
    const int t0 = c * LCH + sub * LSUB;

    __shared__ float sst[2], smn[8], smx[8];
    __shared__ float se[LCH];
    block_minmax(e, sst, smn, smx);

    if (tid < LCH) {
        int t = c * LCH + tid;
        se[tid] = (t == 0) ? 0.0f : (e[b * T_DIM + t - 1] - sst[0]) * sst[1];
    }
    __syncthreads();

    const int seg = (b * NC + c) * NSUB + sub;
    const int oc  = b * NOCT + (c >> 2);
    const __hip_bfloat16* hbp = h_bf + ((size_t)b * T_DIM + t0) * H_DIM + hd;
    __hip_bfloat16* hop = hagg_bf + ((size_t)b * T_DIM + t0) * H_DIM + hd;

    const float pq = Ppre[seg];
    floatx4 soct  = *(const floatx4*)(Soct  + (size_t)oc  * H_DIM + hd);
    floatx4 spart = *(const floatx4*)(Spart + (size_t)seg * H_DIM + hd);
    floatx4 s = pq * soct + spart;
    float sd = fmaf(pq, SDoct[oc], SDpart[seg]);

    #pragma unroll 8
    for (int i = 0; i < LSUB; ++i) {
        float a = se[sub * LSUB + i];
        bf16x4 hb = *(const bf16x4*)(hbp + (size_t)i * H_DIM);
        floatx4 hv;
        #pragma unroll
        for (int k = 0; k < 4; ++k) hv[k] = (float)hb[k];
        s = a * s + hv;
        sd = fmaf(a, sd, 1.0f);
        float inv = 1.0f / sd;
        bf16x4 o;
        #pragma unroll
        for (int k = 0; k < 4; ++k) o[k] = (__bf16)(s[k] * inv);
        *(bf16x4*)(hop + (size_t)i * H_DIM) = o;
    }
}

// ---------------- K5: batched NT-GEMM, C[b,t,s] = (1/sqrt(H)) * A[b,t,:] . B[b,s,:]
// 128x128 tile, 256 threads (4 waves), 32 KB LDS -> 3-4 blocks/CU; inter-block
// wave overlap hides the per-tile barrier drain (measured-best structure here:
// beat coarse-256² (r2, +5µs) and fine-phase-256² (r4, +8µs)).
__device__ __forceinline__ void async16(const void* g, void* l) {
    __builtin_amdgcn_global_load_lds(
        (__attribute__((address_space(1))) void*)g,
        (__attribute__((address_space(3))) void*)l,
        16, 0, 0);
}

__global__ __launch_bounds__(256) void gemm_kernel(
        const __hip_bfloat16* __restrict__ Abf,   // h_bf   [B][T][H]
        const __hip_bfloat16* __restrict__ Bbf,   // hagg_bf[B][T][H]
        float* __restrict__ C) {                  // [B][T][T]
    __shared__ __align__(16) __hip_bfloat16 As[BM * BK];   // 16 KB
    __shared__ __align__(16) __hip_bfloat16 Bs[BN * BK];   // 16 KB

    // Batch-per-XCD pin (id%8 == batch) for L2 locality of the 4 MB A+B set.
    const int id = blockIdx.x + (blockIdx.y << 4) + (blockIdx.z << 8);
    const int b  = id & 7;
    const int tt = id >> 3;
    const int tm = (tt & 15) * BM;
    const int sn = (tt >> 4) * BN;

    const int tid = threadIdx.x;
    const int lane = tid & 63;
    const int wave = tid >> 6;
    const int wm = (wave >> 1) * 64;
    const int wn = (wave & 1) * 64;
    const int l16 = lane & 15;
    const int quad = lane >> 4;

    // Staging: thread tid fills LDS granule (row=tid>>3, slot=tid&7) of each
    // 32-row chunk; slot g holds global k-granule g ^ (row&7)  (XOR swizzle on
    // the GLOBAL side — global_load_lds' LDS dest is fixed base+lane*16).
    const int srow = tid >> 3;
    const int sgran = (tid & 7) ^ (srow & 7);
    const __hip_bfloat16* Ag = Abf + ((size_t)b * T_DIM + tm + srow) * H_DIM + sgran * 8;
    const __hip_bfloat16* Bg = Bbf + ((size_t)b * T_DIM + sn + srow) * H_DIM + sgran * 8;
    char* AsB = (char*)As;
    char* BsB = (char*)Bs;

    floatx4 zero = {0.0f, 0.0f, 0.0f, 0.0f};
    floatx4 acc[4][4];
    #pragma unroll
    for (int i = 0; i < 4; ++i)
        #pragma unroll
        for (int j = 0; j < 4; ++j) acc[i][j] = zero;

    for (int kk = 0; kk < H_DIM; kk += BK) {
        __syncthreads();   // protect previous iteration's LDS reads
        #pragma unroll
        for (int q = 0; q < 4; ++q) {
            async16(Ag + (size_t)q * 32 * H_DIM + kk, AsB + q * 4096 + tid * 16);
            async16(Bg + (size_t)q * 32 * H_DIM + kk, BsB + q * 4096 + tid * 16);
        }
        asm volatile("s_waitcnt vmcnt(0)" ::: "memory");
        __syncthreads();

        bf16x8 af[2][4], bfv[2][4];
        #pragma unroll
        for (int ku = 0; ku < 2; ++ku)
            #pragma unroll
            for (int i = 0; i < 4; ++i) {
                int ra = wm + i * 16 + l16;
                int rb = wn + i * 16 + l16;
                int ga = (ku * 4 + quad) ^ (l16 & 7);
                af[ku][i]  = *reinterpret_cast<const bf16x8*>(AsB + ra * 128 + ga * 16);
                bfv[ku][i] = *reinterpret_cast<const bf16x8*>(BsB + rb * 128 + ga * 16);
            }
        // Swapped operand order (bfv first): transposes D so each lane holds 4
        // CONSECUTIVE s-columns of C[t][s] -> dwordx4 stores.
        #pragma unroll
        for (int ku = 0; ku < 2; ++ku)
            #pragma unroll
            for (int i = 0; i < 4; ++i)
                #pragma unroll
                for (int j = 0; j < 4; ++j)
                    acc[i][j] = __builtin_amdgcn_mfma_f32_16x16x32_bf16(bfv[ku][j], af[ku][i], acc[i][j], 0, 0, 0);
    }

    const float scale = 0.04419417382415922f;  // 1/sqrt(512)
    float* Cp = C + (size_t)b * T_DIM * T_DIM;
    // Swapped-operand D mapping: col(lane&15) -> t (A-row), row(quad*4+r) -> s (B-row).
    #pragma unroll
    for (int i = 0; i < 4; ++i) {
        int row = tm + wm + i * 16 + l16;              // t
        float* crow = Cp + (size_t)row * T_DIM;
        #pragma unroll
        for (int j = 0; j < 4; ++j) {
            int col = sn + wn + j * 16 + quad * 4;     // s base (16B aligned)
            floatx4 v;
            #pragma unroll
            for (int r = 0; r < 4; ++r) v[r] = acc[i][j][r] * scale;
            *(floatx4*)(crow + col) = v;
        }
    }
}

extern "C" void kernel_launch(void* const* d_in, const int* in_sizes, int n_in,
                              void* d_out, int out_size, void* d_ws, size_t ws_size,
                              hipStream_t stream) {
    const float* e = (const float*)d_in[0];
    const float* h = (const float*)d_in[1];
    // d_in[2] (ilens) is unused by the reference output.
    float* out = (float*)d_out;

    char* ws = (char*)d_ws;
    __hip_bfloat16* h_bf    = (__hip_bfloat16*)(ws + 4096);                  // 16 MB
    __hip_bfloat16* hagg_bf = (__hip_bfloat16*)(ws + 4096 + (16u << 20));    // 16 MB
    char* p = ws + 4096 + (32u << 20);
    float* Lsub  = (float*)p;   p += (size_t)B_DIM * NSEG * H_DIM * 4;       // 2 MB
    float* Spart = (float*)p;   p += (size_t)B_DIM * NSEG * H_DIM * 4;       // 2 MB
    float* PPsub = (float*)p;   p += B_DIM * NSEG * 4;                       // 4 KB
    float* LDsub = (float*)p;   p += B_DIM * NSEG * 4;                       // 4 KB
    float* Ppre  = (float*)p;   p += B_DIM * NSEG * 4;                       // 4 KB
    float* SDpart= (float*)p;   p += B_DIM * NSEG * 4;                       // 4 KB
    float* Loct  = (float*)p;   p += (size_t)B_DIM * NOCT * H_DIM * 4;       // 128 KB
    float* Soct  = (float*)p;   p += (size_t)B_DIM * NOCT * H_DIM * 4;       // 128 KB
    float* Poct  = (float*)p;   p += B_DIM * NOCT * 4;                       // 256 B
    float* LDoct = (float*)p;   p += B_DIM * NOCT * 4;                       // 256 B
    float* SDoct = (float*)p;

    chunk_sum_kernel<<<dim3(B_DIM, NC), 512, 0, stream>>>(e, h, h_bf, Lsub, PPsub, LDsub);
    octprefix_kernel<<<dim3(B_DIM, NOCT), 512, 0, stream>>>(Lsub, PPsub, LDsub,
                                                            Spart, Ppre, SDpart,
                                                            Loct, Poct, LDoct);
    octfold_kernel<<<B_DIM, 512, 0, stream>>>(Loct, Poct, LDoct, Soct, SDoct);
    rescan_kernel<<<dim3(B_DIM, NC), 512, 0, stream>>>(e, h_bf, Spart, Ppre, SDpart,
                                                       Soct, SDoct, hagg_bf);
    gemm_kernel<<<dim3(T_DIM / BM, T_DIM / BN, B_DIM), 256, 0, stream>>>(h_bf, hagg_bf, out);
}